// Round 19
// baseline (62.064 us; speedup 1.0000x reference)
//
#include <hip/hip_runtime.h>

// Chamfer loss via MFMA, B=16, N=4096, D=3, fp32 in/out.
// d2[p][q] = ||p||^2 + ||q||^2 - 2 p.q as one 32x32x8 f16 MFMA per tile
// (legacy 2-reg shape; encoding needs only 8 K-slots):
//   k0-3 (lanes 0-31):  A = {pn_h, ax_h, ay_h, az_h},  B = {1, qx_h, qy_h, qz_h}
//   k4-7 (lanes 32-63): A = {pn_l, ax_l, ay_l, az_l},  B = same
// (a = -2p; absmax 0.016 << 0.12 threshold.)
// r19 change vs r17/r18: TWO blocks/CU (grid 512, each 512 cols x 2048 rows,
// row-split combined by uint atomicMin on >=0 floats) -> 32 waves/CU =
// 8 waves/SIMD. __launch_bounds__(1024,8) caps VGPR at 64; K=8 state fits
// (~55 live). Inner loop = r17: depth-1 d-pipeline + 4-deep named A prefetch,
// all indices static (r11/r12 spill lesson).

typedef _Float16 half4    __attribute__((ext_vector_type(4)));
typedef float    floatx16 __attribute__((ext_vector_type(16)));

#define CH_B 16
#define CH_N 4096
#define CH_BLOCK 1024                  // 16 waves
#define CH_COLS 512                    // output cols per block (32/wave)
#define CH_NCT (CH_N / CH_COLS)        // 8 col-tiles per (dir,b)
#define CH_PSPLIT 2
#define CH_ROWS (CH_N / CH_PSPLIT)     // 2048 rows per block
#define CH_CHUNK 1024                  // staged rows per chunk
#define CH_NCHUNK (CH_ROWS / CH_CHUNK) // 2
#define CH_CT (CH_CHUNK / 32)          // 32 row-tiles per chunk
#define CH_NSLICE (2 * CH_B * CH_PSPLIT)  // 64 row-slices
#define CH_NBLK (CH_NSLICE * CH_NCT)   // 512 blocks (2 per CU)

__global__ __launch_bounds__(CH_BLOCK, 8) void chamfer_one(
    const float* __restrict__ src, const float* __restrict__ trg,
    unsigned int* __restrict__ out_all)
{
    __shared__ half4 sp[2][CH_CT * 64];   // 2 x 16 KB A-fragment buffers

    const int tid  = threadIdx.x;
    const int lane = tid & 63;
    const int wave = tid >> 6;            // 0..15
    const int l31  = lane & 31;

    // Same-slice blocks differ by 64 in L -> same (L%8) -> same XCD.
    const int L     = blockIdx.x;         // 0..511
    const int ct    = L >> 6;             // 0..7 col-tile
    const int slice = L & 63;
    const int psl   = slice & 1;
    const int bz    = slice >> 1;         // dir*16 + b
    const int b     = bz & (CH_B - 1);
    const int dir   = bz >> 4;

    const float* P  = dir ? trg : src;
    const float* Q  = dir ? src : trg;
    const float* Pb = P + ((size_t)b * CH_N + (size_t)psl * CH_ROWS) * 3;
    const float* Qb = Q + (size_t)b * CH_N * 3;
    unsigned int* out = out_all + ((size_t)dir * CH_B + b) * CH_N;

    // ---- B fragment: 32 cols per wave, lane-uniform hi-only encoding ----
    const int col0 = ct * CH_COLS + wave * 32 + l31;
    float qn, m = __builtin_inff();
    half4 bfrag;
    {
        const float qx = Qb[col0 * 3 + 0], qy = Qb[col0 * 3 + 1], qz = Qb[col0 * 3 + 2];
        qn = qx * qx + qy * qy + qz * qz;
        bfrag[0] = (_Float16)1.0f;
        bfrag[1] = (_Float16)qx;
        bfrag[2] = (_Float16)qy;
        bfrag[3] = (_Float16)qz;
    }

    // ---- staging: 1 row per thread per chunk (scalar loads) ----
    float pa[3];
    auto loadpts = [&](int c) {
        const float* base = Pb + ((size_t)c * CH_CHUNK + tid) * 3;
        pa[0] = base[0];
        pa[1] = base[1];
        pa[2] = base[2];
    };
    auto writept = [&](int buf) {
        const float ax = -2.0f * pa[0], ay = -2.0f * pa[1], az = -2.0f * pa[2];
        const float pn = pa[0] * pa[0] + pa[1] * pa[1] + pa[2] * pa[2];
        const _Float16 axh = (_Float16)ax, ayh = (_Float16)ay, azh = (_Float16)az;
        const _Float16 pnh = (_Float16)pn;
        const half4 k0 = {pnh, axh, ayh, azh};                       // k 0..3
        const half4 k1 = {(_Float16)(pn - (float)pnh),
                          (_Float16)(ax - (float)axh),
                          (_Float16)(ay - (float)ayh),
                          (_Float16)(az - (float)azh)};              // k 4..7
        sp[buf][(tid >> 5) * 64 + (tid & 31)]      = k0;
        sp[buf][(tid >> 5) * 64 + 32 + (tid & 31)] = k1;
    };

    // prologue: stage chunk 0
    loadpts(0);
    writept(0);
    __syncthreads();

    const floatx16 zero = {0.f,0.f,0.f,0.f,0.f,0.f,0.f,0.f,
                           0.f,0.f,0.f,0.f,0.f,0.f,0.f,0.f};

    // min3-shaped reduction of one MFMA result into m
    auto tree = [&](const floatx16& d) {
        const float u0 = fminf(fminf(d[0],  d[1]),  d[2]);
        const float u1 = fminf(fminf(d[3],  d[4]),  d[5]);
        const float u2 = fminf(fminf(d[6],  d[7]),  d[8]);
        const float u3 = fminf(fminf(d[9],  d[10]), d[11]);
        const float u4 = fminf(fminf(d[12], d[13]), d[14]);
        const float v  = fminf(fminf(u0, u1), u2);
        const float w  = fminf(fminf(u3, u4), d[15]);
        m = fminf(fminf(m, v), w);
    };

    #pragma unroll 1
    for (int c = 0; c < CH_NCHUNK; ++c) {
        const int cur = c & 1;
        const bool more = (c + 1 < CH_NCHUNK);
        if (more) loadpts(c + 1);   // issue early; consumed after compute

        const half4* buf = sp[cur];

        // 4-deep A prefetch + 1-slot d pipeline (max 2 live floatx16)
        half4 A0 = buf[0 * 64 + lane];
        half4 A1 = buf[1 * 64 + lane];
        half4 A2 = buf[2 * 64 + lane];
        half4 A3 = buf[3 * 64 + lane];
        floatx16 d0 = __builtin_amdgcn_mfma_f32_32x32x8f16(A0, bfrag, zero, 0, 0, 0);

        #pragma unroll 1
        for (int t = 0; t <= CH_CT - 8; t += 4) {   // t = 0..24
            floatx16 d1 = __builtin_amdgcn_mfma_f32_32x32x8f16(A1, bfrag, zero, 0, 0, 0);
            A0 = buf[(t + 4) * 64 + lane];
            tree(d0);
            floatx16 d2 = __builtin_amdgcn_mfma_f32_32x32x8f16(A2, bfrag, zero, 0, 0, 0);
            A1 = buf[(t + 5) * 64 + lane];
            tree(d1);
            floatx16 d3 = __builtin_amdgcn_mfma_f32_32x32x8f16(A3, bfrag, zero, 0, 0, 0);
            A2 = buf[(t + 6) * 64 + lane];
            tree(d2);
            d0 = __builtin_amdgcn_mfma_f32_32x32x8f16(A0, bfrag, zero, 0, 0, 0);
            A3 = buf[(t + 7) * 64 + lane];
            tree(d3);
        }
        // epilogue: tiles CT-4..CT-1 (d0 already holds tile CT-4's result)
        {
            floatx16 e1 = __builtin_amdgcn_mfma_f32_32x32x8f16(A1, bfrag, zero, 0, 0, 0);
            tree(d0);
            floatx16 e2 = __builtin_amdgcn_mfma_f32_32x32x8f16(A2, bfrag, zero, 0, 0, 0);
            tree(e1);
            floatx16 e3 = __builtin_amdgcn_mfma_f32_32x32x8f16(A3, bfrag, zero, 0, 0, 0);
            tree(e2);
            tree(e3);
        }

        if (more) writept(cur ^ 1);   // LDS writes late (load latency hidden)
        __syncthreads();
    }

    // ---- epilogue: add ||q||^2, clamp >=0, fold row-halves, atomicMin ----
    float v = fmaxf(m + qn, 0.0f);
    v = fminf(v, __shfl_xor(v, 32));
    if (lane < 32) atomicMin(&out[col0], __float_as_uint(v));
}

extern "C" void kernel_launch(void* const* d_in, const int* in_sizes, int n_in,
                              void* d_out, int out_size, void* d_ws, size_t ws_size,
                              hipStream_t stream) {
    const float* src = (const float*)d_in[0];
    const float* trg = (const float*)d_in[1];
    unsigned int* out = (unsigned int*)d_out;

    // Init outputs to 0x7f7f7f7f (~3.4e38): valid +inf under uint-ordered min
    // for nonnegative values.
    hipMemsetAsync(out, 0x7f, (size_t)2 * CH_B * CH_N * sizeof(float), stream);

    chamfer_one<<<dim3(CH_NBLK), dim3(CH_BLOCK), 0, stream>>>(src, trg, out);
}

// Round 20
// 48.378 us; speedup vs baseline: 1.2829x; 1.2829x over previous
//
#include <hip/hip_runtime.h>

// Chamfer loss via MFMA, B=16, N=4096, D=3, fp32 in/out. Single dispatch.
// d2[p][q] = ||p||^2 + ||q||^2 - 2 p.q as one 32x32x8 f16 MFMA per tile
// (legacy 2-reg shape; encoding needs only 8 K-slots):
//   k0-3 (lanes 0-31):  A = {pn_h, ax_h, ay_h, az_h},  B = {1, qx_h, qy_h, qz_h}
//   k4-7 (lanes 32-63): A = {pn_l, ax_l, ay_l, az_l},  B = same
// (a = -2p; absmax 0.016 << 0.12 threshold.)
// Structure = r17 (18.3us) with ONE change: 8-DEEP named A prefetch
// (A0..A7). Read->consume distance ~7-8 tiles (~160+ issue-cyc) now exceeds
// loaded ds_read latency (~120-200cyc), taking lgkmcnt waits off the per-tile
// critical path. Depth-1 d pipeline; max 2 live floatx16; all indices static
// (r11/r12/r19 spill lessons).

typedef _Float16 half4    __attribute__((ext_vector_type(4)));
typedef float    floatx16 __attribute__((ext_vector_type(16)));

#define CH_B 16
#define CH_N 4096
#define CH_BLOCK 1024                  // 16 waves
#define CH_COLS 512                    // output cols per block (32/wave)
#define CH_NCT (CH_N / CH_COLS)        // 8 col-tiles per (dir,b)
#define CH_CHUNK 1024                  // staged rows per chunk
#define CH_NCHUNK (CH_N / CH_CHUNK)    // 4
#define CH_CT (CH_CHUNK / 32)          // 32 row-tiles per chunk
#define CH_NBLK (2 * CH_B * CH_NCT)    // 256 blocks (1 per CU)

__global__ __launch_bounds__(CH_BLOCK, 4) void chamfer_one(
    const float* __restrict__ src, const float* __restrict__ trg,
    float* __restrict__ out_all)
{
    __shared__ half4 sp[2][CH_CT * 64];   // 2 x 16 KB A-fragment buffers

    const int tid  = threadIdx.x;
    const int lane = tid & 63;
    const int wave = tid >> 6;            // 0..15
    const int l31  = lane & 31;

    const int L   = blockIdx.x;           // 0..255
    const int ct  = L & (CH_NCT - 1);     // col-tile
    const int bz  = L >> 3;               // dir*16 + b
    const int b   = bz & (CH_B - 1);
    const int dir = bz >> 4;

    const float* P  = dir ? trg : src;
    const float* Q  = dir ? src : trg;
    const float* Pb = P + (size_t)b * CH_N * 3;
    const float* Qb = Q + (size_t)b * CH_N * 3;
    float* out = out_all + ((size_t)dir * CH_B + b) * CH_N;

    // ---- B fragment: 32 cols per wave, lane-uniform hi-only encoding ----
    const int col0 = ct * CH_COLS + wave * 32 + l31;
    float qn, m = __builtin_inff();
    half4 bfrag;
    {
        const float qx = Qb[col0 * 3 + 0], qy = Qb[col0 * 3 + 1], qz = Qb[col0 * 3 + 2];
        qn = qx * qx + qy * qy + qz * qz;
        bfrag[0] = (_Float16)1.0f;
        bfrag[1] = (_Float16)qx;
        bfrag[2] = (_Float16)qy;
        bfrag[3] = (_Float16)qz;
    }

    // ---- staging: 1 row per thread per chunk (scalar loads) ----
    float pa[3];
    auto loadpts = [&](int c) {
        const float* base = Pb + ((size_t)c * CH_CHUNK + tid) * 3;
        pa[0] = base[0];
        pa[1] = base[1];
        pa[2] = base[2];
    };
    auto writept = [&](int buf) {
        const float ax = -2.0f * pa[0], ay = -2.0f * pa[1], az = -2.0f * pa[2];
        const float pn = pa[0] * pa[0] + pa[1] * pa[1] + pa[2] * pa[2];
        const _Float16 axh = (_Float16)ax, ayh = (_Float16)ay, azh = (_Float16)az;
        const _Float16 pnh = (_Float16)pn;
        const half4 k0 = {pnh, axh, ayh, azh};                       // k 0..3
        const half4 k1 = {(_Float16)(pn - (float)pnh),
                          (_Float16)(ax - (float)axh),
                          (_Float16)(ay - (float)ayh),
                          (_Float16)(az - (float)azh)};              // k 4..7
        sp[buf][(tid >> 5) * 64 + (tid & 31)]      = k0;
        sp[buf][(tid >> 5) * 64 + 32 + (tid & 31)] = k1;
    };

    // prologue: stage chunk 0
    loadpts(0);
    writept(0);
    __syncthreads();

    const floatx16 zero = {0.f,0.f,0.f,0.f,0.f,0.f,0.f,0.f,
                           0.f,0.f,0.f,0.f,0.f,0.f,0.f,0.f};

    // min3-shaped reduction of one MFMA result into m
    auto tree = [&](const floatx16& d) {
        const float u0 = fminf(fminf(d[0],  d[1]),  d[2]);
        const float u1 = fminf(fminf(d[3],  d[4]),  d[5]);
        const float u2 = fminf(fminf(d[6],  d[7]),  d[8]);
        const float u3 = fminf(fminf(d[9],  d[10]), d[11]);
        const float u4 = fminf(fminf(d[12], d[13]), d[14]);
        const float v  = fminf(fminf(u0, u1), u2);
        const float w  = fminf(fminf(u3, u4), d[15]);
        m = fminf(fminf(m, v), w);
    };

    #pragma unroll 1
    for (int c = 0; c < CH_NCHUNK; ++c) {
        const int cur = c & 1;
        const bool more = (c + 1 < CH_NCHUNK);
        if (more) loadpts(c + 1);   // issue early; consumed after compute

        const half4* buf = sp[cur];

        // 8-deep A prefetch (tiles 0..7), depth-1 d pipeline
        half4 A0 = buf[0 * 64 + lane];
        half4 A1 = buf[1 * 64 + lane];
        half4 A2 = buf[2 * 64 + lane];
        half4 A3 = buf[3 * 64 + lane];
        half4 A4 = buf[4 * 64 + lane];
        half4 A5 = buf[5 * 64 + lane];
        half4 A6 = buf[6 * 64 + lane];
        half4 A7 = buf[7 * 64 + lane];
        floatx16 d0 = __builtin_amdgcn_mfma_f32_32x32x8f16(A0, bfrag, zero, 0, 0, 0);

        #pragma unroll 1
        for (int t = 0; t <= CH_CT - 16; t += 8) {   // t = 0,8,16
            floatx16 d1 = __builtin_amdgcn_mfma_f32_32x32x8f16(A1, bfrag, zero, 0, 0, 0);
            A0 = buf[(t + 8) * 64 + lane];
            tree(d0);
            floatx16 d2 = __builtin_amdgcn_mfma_f32_32x32x8f16(A2, bfrag, zero, 0, 0, 0);
            A1 = buf[(t + 9) * 64 + lane];
            tree(d1);
            floatx16 d3 = __builtin_amdgcn_mfma_f32_32x32x8f16(A3, bfrag, zero, 0, 0, 0);
            A2 = buf[(t + 10) * 64 + lane];
            tree(d2);
            floatx16 d4 = __builtin_amdgcn_mfma_f32_32x32x8f16(A4, bfrag, zero, 0, 0, 0);
            A3 = buf[(t + 11) * 64 + lane];
            tree(d3);
            floatx16 d5 = __builtin_amdgcn_mfma_f32_32x32x8f16(A5, bfrag, zero, 0, 0, 0);
            A4 = buf[(t + 12) * 64 + lane];
            tree(d4);
            floatx16 d6 = __builtin_amdgcn_mfma_f32_32x32x8f16(A6, bfrag, zero, 0, 0, 0);
            A5 = buf[(t + 13) * 64 + lane];
            tree(d5);
            floatx16 d7 = __builtin_amdgcn_mfma_f32_32x32x8f16(A7, bfrag, zero, 0, 0, 0);
            A6 = buf[(t + 14) * 64 + lane];
            tree(d6);
            d0 = __builtin_amdgcn_mfma_f32_32x32x8f16(A0, bfrag, zero, 0, 0, 0);
            A7 = buf[(t + 15) * 64 + lane];
            tree(d7);
        }
        // epilogue: d0 = tile CT-8's result; A1..A7 hold tiles CT-7..CT-1
        {
            floatx16 e1 = __builtin_amdgcn_mfma_f32_32x32x8f16(A1, bfrag, zero, 0, 0, 0);
            tree(d0);
            floatx16 e2 = __builtin_amdgcn_mfma_f32_32x32x8f16(A2, bfrag, zero, 0, 0, 0);
            tree(e1);
            floatx16 e3 = __builtin_amdgcn_mfma_f32_32x32x8f16(A3, bfrag, zero, 0, 0, 0);
            tree(e2);
            floatx16 e4 = __builtin_amdgcn_mfma_f32_32x32x8f16(A4, bfrag, zero, 0, 0, 0);
            tree(e3);
            floatx16 e5 = __builtin_amdgcn_mfma_f32_32x32x8f16(A5, bfrag, zero, 0, 0, 0);
            tree(e4);
            floatx16 e6 = __builtin_amdgcn_mfma_f32_32x32x8f16(A6, bfrag, zero, 0, 0, 0);
            tree(e5);
            floatx16 e7 = __builtin_amdgcn_mfma_f32_32x32x8f16(A7, bfrag, zero, 0, 0, 0);
            tree(e6);
            tree(e7);
        }

        if (more) writept(cur ^ 1);   // LDS writes late (load latency hidden)
        __syncthreads();
    }

    // ---- epilogue: add ||q||^2, clamp >=0, fold row-halves, plain store ----
    float v = fmaxf(m + qn, 0.0f);
    v = fminf(v, __shfl_xor(v, 32));
    if (lane < 32) out[col0] = v;
}

extern "C" void kernel_launch(void* const* d_in, const int* in_sizes, int n_in,
                              void* d_out, int out_size, void* d_ws, size_t ws_size,
                              hipStream_t stream) {
    const float* src = (const float*)d_in[0];
    const float* trg = (const float*)d_in[1];
    float* out = (float*)d_out;

    chamfer_one<<<dim3(CH_NBLK), dim3(CH_BLOCK), 0, stream>>>(src, trg, out);
}

// Round 22
// 18.357 us; speedup vs baseline: 3.3810x; 2.6355x over previous
//
#include <hip/hip_runtime.h>

// Chamfer loss via MFMA, B=16, N=4096, D=3, fp32 in/out. Single dispatch.
// d2[p][q] = ||p||^2 + ||q||^2 - 2 p.q as one 32x32x8 f16 MFMA per tile
// (legacy 2-reg shape; encoding needs only 8 K-slots).
//   k0-3 (lanes 0-31):  A = {pn_h, ax_h, ay_h, az_h},  B = {1, qx_h, qy_h, qz_h}
//   k4-7 (lanes 32-63): A = {pn_l, ax_l, ay_l, az_l},  B = {1, qx_h, qy_h, qz_h}
// (a = -2p; A-side hi/lo corrected, B hi-only: absmax 0.016 << 0.12 thr.)
// FINAL (= r18, best verified 18.2us): 1024-thread blocks (16 waves =
// 4 waves/SIMD), 1 block/CU, 512 cols/block, 4 double-buffered 1024-row LDS
// chunks, 2-slot software-pipelined accumulator + 4-deep named A prefetch.
// Max 3 live floatx16; all register indices static.
// Lessons encoded: >4 live MFMA results spills (r11/r12/r19/r20); inline-asm
// reads of MFMA dests skip hazard wait-states -> wrong results (r21); LDS
// BW/latency, barriers, MFMA latency all verified non-binding (r13-r20).

typedef _Float16 half4    __attribute__((ext_vector_type(4)));
typedef float    floatx16 __attribute__((ext_vector_type(16)));

#define CH_B 16
#define CH_N 4096
#define CH_BLOCK 1024                  // 16 waves
#define CH_COLS 512                    // output cols per block (32/wave)
#define CH_NCT (CH_N / CH_COLS)        // 8 col-tiles per (dir,b)
#define CH_CHUNK 1024                  // staged rows per chunk
#define CH_NCHUNK (CH_N / CH_CHUNK)    // 4
#define CH_CT (CH_CHUNK / 32)          // 32 row-tiles per chunk
#define CH_NBLK (2 * CH_B * CH_NCT)    // 256 blocks (1 per CU)

__global__ __launch_bounds__(CH_BLOCK, 4) void chamfer_one(
    const float* __restrict__ src, const float* __restrict__ trg,
    float* __restrict__ out_all)
{
    __shared__ half4 sp[2][CH_CT * 64];   // 2 x 16 KB A-fragment buffers

    const int tid  = threadIdx.x;
    const int lane = tid & 63;
    const int wave = tid >> 6;            // 0..15
    const int l31  = lane & 31;

    const int L   = blockIdx.x;           // 0..255
    const int ct  = L & (CH_NCT - 1);     // col-tile
    const int bz  = L >> 3;               // dir*16 + b
    const int b   = bz & (CH_B - 1);
    const int dir = bz >> 4;

    const float* P  = dir ? trg : src;
    const float* Q  = dir ? src : trg;
    const float* Pb = P + (size_t)b * CH_N * 3;
    const float* Qb = Q + (size_t)b * CH_N * 3;
    float* out = out_all + ((size_t)dir * CH_B + b) * CH_N;

    // ---- B fragment: 32 cols per wave, lane-uniform hi-only encoding ----
    const int col0 = ct * CH_COLS + wave * 32 + l31;
    float qn, m = __builtin_inff();
    half4 bfrag;
    {
        const float qx = Qb[col0 * 3 + 0], qy = Qb[col0 * 3 + 1], qz = Qb[col0 * 3 + 2];
        qn = qx * qx + qy * qy + qz * qz;
        bfrag[0] = (_Float16)1.0f;
        bfrag[1] = (_Float16)qx;
        bfrag[2] = (_Float16)qy;
        bfrag[3] = (_Float16)qz;
    }

    // ---- staging: 1 row per thread per chunk (scalar loads) ----
    float pa[3];
    auto loadpts = [&](int c) {
        const float* base = Pb + ((size_t)c * CH_CHUNK + tid) * 3;
        pa[0] = base[0];
        pa[1] = base[1];
        pa[2] = base[2];
    };
    auto writept = [&](int buf) {
        const float ax = -2.0f * pa[0], ay = -2.0f * pa[1], az = -2.0f * pa[2];
        const float pn = pa[0] * pa[0] + pa[1] * pa[1] + pa[2] * pa[2];
        const _Float16 axh = (_Float16)ax, ayh = (_Float16)ay, azh = (_Float16)az;
        const _Float16 pnh = (_Float16)pn;
        const half4 k0 = {pnh, axh, ayh, azh};                       // k 0..3
        const half4 k1 = {(_Float16)(pn - (float)pnh),
                          (_Float16)(ax - (float)axh),
                          (_Float16)(ay - (float)ayh),
                          (_Float16)(az - (float)azh)};              // k 4..7
        sp[buf][(tid >> 5) * 64 + (tid & 31)]      = k0;
        sp[buf][(tid >> 5) * 64 + 32 + (tid & 31)] = k1;
    };

    // prologue: stage chunk 0
    loadpts(0);
    writept(0);
    __syncthreads();

    const floatx16 zero = {0.f,0.f,0.f,0.f,0.f,0.f,0.f,0.f,
                           0.f,0.f,0.f,0.f,0.f,0.f,0.f,0.f};

    // min3-shaped reduction of one MFMA result into m
    auto tree = [&](const floatx16& d) {
        const float u0 = fminf(fminf(d[0],  d[1]),  d[2]);
        const float u1 = fminf(fminf(d[3],  d[4]),  d[5]);
        const float u2 = fminf(fminf(d[6],  d[7]),  d[8]);
        const float u3 = fminf(fminf(d[9],  d[10]), d[11]);
        const float u4 = fminf(fminf(d[12], d[13]), d[14]);
        const float v  = fminf(fminf(u0, u1), u2);
        const float w  = fminf(fminf(u3, u4), d[15]);
        m = fminf(fminf(m, v), w);
    };

    #pragma unroll 1
    for (int c = 0; c < CH_NCHUNK; ++c) {
        const int cur = c & 1;
        const bool more = (c + 1 < CH_NCHUNK);
        if (more) loadpts(c + 1);   // issue early; consumed after compute

        const half4* buf = sp[cur];

        // 4-deep A prefetch + 2-slot d pipeline (max 3 live floatx16)
        half4 A0 = buf[0 * 64 + lane];
        half4 A1 = buf[1 * 64 + lane];
        half4 A2 = buf[2 * 64 + lane];
        half4 A3 = buf[3 * 64 + lane];
        floatx16 d0 = __builtin_amdgcn_mfma_f32_32x32x8f16(A0, bfrag, zero, 0, 0, 0);
        floatx16 d1 = __builtin_amdgcn_mfma_f32_32x32x8f16(A1, bfrag, zero, 0, 0, 0);

        #pragma unroll 1
        for (int t = 0; t <= CH_CT - 8; t += 4) {   // t = 0..24
            floatx16 d2 = __builtin_amdgcn_mfma_f32_32x32x8f16(A2, bfrag, zero, 0, 0, 0);
            A0 = buf[(t + 4) * 64 + lane];
            tree(d0);
            floatx16 d3 = __builtin_amdgcn_mfma_f32_32x32x8f16(A3, bfrag, zero, 0, 0, 0);
            A1 = buf[(t + 5) * 64 + lane];
            tree(d1);
            d0 = __builtin_amdgcn_mfma_f32_32x32x8f16(A0, bfrag, zero, 0, 0, 0);
            A2 = buf[(t + 6) * 64 + lane];
            tree(d2);
            d1 = __builtin_amdgcn_mfma_f32_32x32x8f16(A1, bfrag, zero, 0, 0, 0);
            A3 = buf[(t + 7) * 64 + lane];
            tree(d3);
        }
        // epilogue: d0=tile CT-4, d1=tile CT-3; A2,A3 hold tiles CT-2, CT-1
        {
            floatx16 e2 = __builtin_amdgcn_mfma_f32_32x32x8f16(A2, bfrag, zero, 0, 0, 0);
            tree(d0);
            floatx16 e3 = __builtin_amdgcn_mfma_f32_32x32x8f16(A3, bfrag, zero, 0, 0, 0);
            tree(d1);
            tree(e2);
            tree(e3);
        }

        if (more) writept(cur ^ 1);   // LDS writes late (load latency hidden)
        __syncthreads();
    }

    // ---- epilogue: add ||q||^2, clamp >=0, fold row-halves, plain store ----
    float v = fmaxf(m + qn, 0.0f);
    v = fminf(v, __shfl_xor(v, 32));
    if (lane < 32) out[col0] = v;
}

extern "C" void kernel_launch(void* const* d_in, const int* in_sizes, int n_in,
                              void* d_out, int out_size, void* d_ws, size_t ws_size,
                              hipStream_t stream) {
    const float* src = (const float*)d_in[0];
    const float* trg = (const float*)d_in[1];
    float* out = (float*)d_out;

    chamfer_one<<<dim3(CH_NBLK), dim3(CH_BLOCK), 0, stream>>>(src, trg, out);
}